// Round 1
// baseline (20528.038 us; speedup 1.0000x reference)
//
#include <hip/hip_runtime.h>
#include <hip/hip_bf16.h>

// ESN scan: h_{t+1} = 0.1*h_t + 0.9*tanh(x_t @ W_in^T + b + h_t @ W^T)
// B=32, T=1000, D_IN=64, H=1024. Single persistent cooperative kernel,
// custom grid barrier per step, bf16 MFMA (16x16x32) with fused input proj.

#define B_    32
#define T_    1000
#define D_    64
#define H_    1024
#define KP    1152          // padded K: 1024 (h) + 64 (x) + 64 (zero pad)
#define GRID  128
#define NTHR  256
#define LRATE 0.9f

typedef __bf16 bf16_t;
typedef __bf16 bf16x8 __attribute__((ext_vector_type(8)));
typedef float  f32x4  __attribute__((ext_vector_type(4)));

// ws layout: arrive[256] ints @0 ; hbuf0 @1024 ; hbuf1 ; wext
#define HBUF_BYTES (B_ * KP * 2)
#define OFF_HBUF0  1024
#define OFF_HBUF1  (1024 + HBUF_BYTES)
#define OFF_WEXT   (1024 + 2 * HBUF_BYTES)

__device__ __forceinline__ void grid_barrier(int* arrive, int bid, int tid, int target) {
    // release: make this block's h/x/out stores visible device-wide
    __builtin_amdgcn_fence(__ATOMIC_RELEASE, "agent");
    __syncthreads();
    if (tid < 64) {
        if (tid == 0)
            __hip_atomic_store(&arrive[bid], target, __ATOMIC_RELAXED, __HIP_MEMORY_SCOPE_AGENT);
        for (;;) {
            int v0 = __hip_atomic_load(&arrive[tid],      __ATOMIC_RELAXED, __HIP_MEMORY_SCOPE_AGENT);
            int v1 = __hip_atomic_load(&arrive[tid + 64], __ATOMIC_RELAXED, __HIP_MEMORY_SCOPE_AGENT);
            if (__all((v0 >= target) & (v1 >= target))) break;
            __builtin_amdgcn_s_sleep(1);
        }
    }
    __syncthreads();
    // acquire: invalidate stale L1/L2 so normal loads see fresh h from other XCDs
    __builtin_amdgcn_fence(__ATOMIC_ACQUIRE, "agent");
}

__global__ __launch_bounds__(NTHR, 1) void esn_scan(
    const float* __restrict__ x,     // [B, T, D]
    const float* __restrict__ Win,   // [H, D]
    const float* __restrict__ bias,  // [H]
    const float* __restrict__ W,     // [H, H]
    float* __restrict__ out,         // [B, T, H]
    unsigned char* wsb)
{
    int*    arrive = (int*)wsb;
    bf16_t* hbuf0  = (bf16_t*)(wsb + OFF_HBUF0);
    bf16_t* hbuf1  = (bf16_t*)(wsb + OFF_HBUF1);
    bf16_t* wext   = (bf16_t*)(wsb + OFF_WEXT);

    const int bid = blockIdx.x;
    const int tid = threadIdx.x;

    // ---------------- init phase ----------------
    // wext[h][0:1024]=W[h][:], [1024:1088]=Win[h][:], [1088:1152]=0  (bf16)
    {
        const int rows = H_ / GRID;           // 8 rows per block
        const int r0 = bid * rows;
        for (int r = r0; r < r0 + rows; ++r) {
            for (int c = tid; c < KP; c += NTHR) {
                float v = 0.f;
                if (c < H_)            v = W[r * H_ + c];
                else if (c < H_ + D_)  v = Win[r * D_ + (c - H_)];
                wext[r * KP + c] = (bf16_t)v;
            }
        }
        // hbuf0 row b: h-region = 0 (h_0 = 0), x-region = x[b,0,:], pad = 0.
        // hbuf1: zero everything (h/x overwritten during step 0 anyway).
        if (bid < B_) {
            for (int c = tid; c < KP; c += NTHR) {
                float v0 = 0.f;
                if (c >= H_ && c < H_ + D_) v0 = x[bid * (T_ * D_) + (c - H_)];
                hbuf0[bid * KP + c] = (bf16_t)v0;
                hbuf1[bid * KP + c] = (bf16_t)0.f;
            }
        }
    }
    grid_barrier(arrive, bid, tid, 1);

    // ---------------- scan phase ----------------
    const int mt   = bid & 1;          // M-tile: batches [mt*16, mt*16+16)
    const int h0   = (bid >> 1) * 16;  // h-slice: [h0, h0+16)
    const int lane = tid & 63;
    const int wv   = tid >> 6;         // wave id 0..3 -> K quarter
    const int mcol = lane & 15;        // MFMA: A row / B col / both = lane&15
    const int quad = lane >> 4;

    __shared__ float lds[4 * 256];

    // A frag: A[m][k] = hbuf_cur[(mt*16+m)*KP + k], lane holds k = k0 + quad*8 + j
    // B frag: B[k][n] = wext[(h0+n)*KP + k], same per-lane k mapping
    const int     a_off = (mt * 16 + mcol) * KP + quad * 8 + wv * (9 * 32);
    const bf16_t* Bb    = wext + (h0 + mcol) * KP + quad * 8 + wv * (9 * 32);

    // epilogue mapping: thread tid -> (row=batch, col=h) of the 16x16 C tile
    const int   er = tid >> 4, ec = tid & 15;
    const int   bat_e = mt * 16 + er;
    const int   h_e   = h0 + ec;
    const float bias_h = bias[h_e];    // register-resident for the whole scan

    for (int t = 0; t < T_; ++t) {
        const bf16_t* cur = (t & 1) ? hbuf1 : hbuf0;
        bf16_t*       nxt = (t & 1) ? hbuf0 : hbuf1;
        const bf16_t* Ab  = cur + a_off;

        f32x4 acc = {0.f, 0.f, 0.f, 0.f};
        #pragma unroll
        for (int kc = 0; kc < 9; ++kc) {
            bf16x8 av = *(const bf16x8*)(Ab + kc * 32);
            bf16x8 bv = *(const bf16x8*)(Bb + kc * 32);
            acc = __builtin_amdgcn_mfma_f32_16x16x32_bf16(av, bv, acc, 0, 0, 0);
        }

        // cross-wave K reduction via LDS. C/D layout: col=lane&15, row=quad*4+i
        #pragma unroll
        for (int i = 0; i < 4; ++i)
            lds[wv * 256 + (quad * 4 + i) * 16 + mcol] = acc[i];
        __syncthreads();

        {
            float u  = lds[tid] + lds[256 + tid] + lds[512 + tid] + lds[768 + tid] + bias_h;
            float hp = (float)cur[bat_e * KP + h_e];
            float th = tanhf(u);
            float hn = (1.f - LRATE) * hp + LRATE * th;
            out[bat_e * (T_ * H_) + t * H_ + h_e] = hn;      // hs[b, t, h] = h_{t+1}
            nxt[bat_e * KP + h_e] = (bf16_t)hn;
        }

        // stage x_{t+1} (bf16) into nxt's x-region: block bid covers 16 elems
        if (t + 1 < T_ && tid < 16) {
            int bx = bid >> 2;
            int d  = (bid & 3) * 16 + tid;
            nxt[bx * KP + H_ + d] = (bf16_t)x[bx * (T_ * D_) + (t + 1) * D_ + d];
        }

        if (t + 1 < T_)
            grid_barrier(arrive, bid, tid, t + 2);
    }
}

extern "C" void kernel_launch(void* const* d_in, const int* in_sizes, int n_in,
                              void* d_out, int out_size, void* d_ws, size_t ws_size,
                              hipStream_t stream) {
    (void)in_sizes; (void)n_in; (void)out_size; (void)ws_size;
    const float* x    = (const float*)d_in[0];
    const float* Win  = (const float*)d_in[1];
    const float* bias = (const float*)d_in[2];
    const float* W    = (const float*)d_in[3];
    float*       out  = (float*)d_out;
    void*        ws   = d_ws;

    void* args[] = { (void*)&x, (void*)&Win, (void*)&bias, (void*)&W, (void*)&out, (void*)&ws };
    hipLaunchCooperativeKernel((const void*)esn_scan, dim3(GRID), dim3(NTHR), args, 0, stream);
}

// Round 2
// 7632.444 us; speedup vs baseline: 2.6896x; 2.6896x over previous
//
#include <hip/hip_runtime.h>
#include <hip/hip_bf16.h>

// ESN scan: h_{t+1} = 0.1*h_t + 0.9*tanh(x_t @ W_in^T + b + h_t @ W^T)
// B=32, T=1000, D_IN=64, H=1024. Persistent cooperative kernel, per-step grid
// barrier. R2: no per-step agent fences (they lowered to full L2 inv/wb and
// caused 171 MB of Wext re-fetch). Cross-block h/x exchange now uses relaxed
// agent-scope atomics (cache-bypassing, coherent at Infinity Cache); Wext
// stays L1/L2-resident. h_prev carried in f32 register per thread.

#define B_    32
#define T_    1000
#define D_    64
#define H_    1024
#define KP    1152          // padded K: 1024 (h) + 64 (x) + 64 (zero pad)
#define GRID  128
#define NTHR  256
#define LRATE 0.9f

typedef __bf16 bf16_t;
typedef __bf16 bf16x8 __attribute__((ext_vector_type(8)));
typedef float  f32x4  __attribute__((ext_vector_type(4)));
typedef unsigned long long u64;

// ws layout: arrive[256] ints @0 ; hbuf0 @1024 ; hbuf1 ; wext
#define HBUF_BYTES (B_ * KP * 2)
#define OFF_HBUF0  1024
#define OFF_HBUF1  (1024 + HBUF_BYTES)
#define OFF_WEXT   (1024 + 2 * HBUF_BYTES)

__device__ __forceinline__ unsigned pack_bf16(float a, float b) {
    unsigned short lo = __builtin_bit_cast(unsigned short, (bf16_t)a);
    unsigned short hi = __builtin_bit_cast(unsigned short, (bf16_t)b);
    return (unsigned)lo | ((unsigned)hi << 16);
}

// Init-only barrier: full release/acquire agent fences (makes the normally-
// stored Wext visible device-wide, once).
__device__ __forceinline__ void grid_barrier_fenced(int* arrive, int bid, int tid, int target) {
    __builtin_amdgcn_fence(__ATOMIC_RELEASE, "agent");
    __syncthreads();
    if (tid < 64) {
        if (tid == 0)
            __hip_atomic_store(&arrive[bid], target, __ATOMIC_RELAXED, __HIP_MEMORY_SCOPE_AGENT);
        for (;;) {
            int v0 = __hip_atomic_load(&arrive[tid],      __ATOMIC_RELAXED, __HIP_MEMORY_SCOPE_AGENT);
            int v1 = __hip_atomic_load(&arrive[tid + 64], __ATOMIC_RELAXED, __HIP_MEMORY_SCOPE_AGENT);
            if (__all((v0 >= target) & (v1 >= target))) break;
            __builtin_amdgcn_s_sleep(1);
        }
    }
    __syncthreads();
    __builtin_amdgcn_fence(__ATOMIC_ACQUIRE, "agent");
}

// Steady-state barrier: NO cache-flushing fences. All cross-block data moves
// via sc-coherent atomics; s_waitcnt(0) makes them globally visible before
// the arrive-flag store. `out` needs no fence (read only after kernel end).
__device__ __forceinline__ void grid_barrier_fast(int* arrive, int bid, int tid, int target) {
    __builtin_amdgcn_s_waitcnt(0);   // drain vm+lgkm: h/x atomic stores are visible
    __syncthreads();
    if (tid < 64) {
        if (tid == 0)
            __hip_atomic_store(&arrive[bid], target, __ATOMIC_RELAXED, __HIP_MEMORY_SCOPE_AGENT);
        for (;;) {
            int v0 = __hip_atomic_load(&arrive[tid],      __ATOMIC_RELAXED, __HIP_MEMORY_SCOPE_AGENT);
            int v1 = __hip_atomic_load(&arrive[tid + 64], __ATOMIC_RELAXED, __HIP_MEMORY_SCOPE_AGENT);
            if (__all((v0 >= target) & (v1 >= target))) break;
            __builtin_amdgcn_s_sleep(1);
        }
    }
    __builtin_amdgcn_fence(__ATOMIC_ACQUIRE, "workgroup");  // compiler ordering only
    __syncthreads();
}

__global__ __launch_bounds__(NTHR, 1) void esn_scan(
    const float* __restrict__ x,     // [B, T, D]
    const float* __restrict__ Win,   // [H, D]
    const float* __restrict__ bias,  // [H]
    const float* __restrict__ W,     // [H, H]
    float* __restrict__ out,         // [B, T, H]
    unsigned char* wsb)
{
    int*    arrive = (int*)wsb;
    bf16_t* hbuf0  = (bf16_t*)(wsb + OFF_HBUF0);
    bf16_t* hbuf1  = (bf16_t*)(wsb + OFF_HBUF1);
    bf16_t* wext   = (bf16_t*)(wsb + OFF_WEXT);

    const int bid = blockIdx.x;
    const int tid = threadIdx.x;

    // ---------------- init phase ----------------
    // wext[h][0:1024]=W[h][:], [1024:1088]=Win[h][:], [1088:1152]=0  (bf16)
    // Normal stores: made visible once by the fenced barrier below, then
    // read-only (cached in L1/L2) for the rest of the scan.
    {
        const int rows = H_ / GRID;           // 8 rows per block
        const int r0 = bid * rows;
        for (int r = r0; r < r0 + rows; ++r) {
            for (int c = tid; c < KP; c += NTHR) {
                float v = 0.f;
                if (c < H_)            v = W[r * H_ + c];
                else if (c < H_ + D_)  v = Win[r * D_ + (c - H_)];
                wext[r * KP + c] = (bf16_t)v;
            }
        }
        // hbuf rows: coherent atomic stores (they'll be read via coherent
        // atomic loads each step — must not sit dirty in L2).
        if (bid < B_) {
            for (int c = tid * 2; c < KP; c += NTHR * 2) {
                float v0 = 0.f, v1 = 0.f;
                if (c     >= H_ && c     < H_ + D_) v0 = x[bid * (T_ * D_) + (c     - H_)];
                if (c + 1 >= H_ && c + 1 < H_ + D_) v1 = x[bid * (T_ * D_) + (c + 1 - H_)];
                __hip_atomic_store((unsigned*)(hbuf0 + bid * KP + c), pack_bf16(v0, v1),
                                   __ATOMIC_RELAXED, __HIP_MEMORY_SCOPE_AGENT);
                __hip_atomic_store((unsigned*)(hbuf1 + bid * KP + c), 0u,
                                   __ATOMIC_RELAXED, __HIP_MEMORY_SCOPE_AGENT);
            }
        }
    }
    grid_barrier_fenced(arrive, bid, tid, 1);

    // ---------------- scan phase ----------------
    const int mt   = bid & 1;          // M-tile: batches [mt*16, mt*16+16)
    const int h0   = (bid >> 1) * 16;  // h-slice: [h0, h0+16)
    const int lane = tid & 63;
    const int wv   = tid >> 6;         // wave id 0..3 -> K quarter
    const int mcol = lane & 15;
    const int quad = lane >> 4;

    __shared__ float lds[4 * 256];

    const int     a_off = (mt * 16 + mcol) * KP + quad * 8 + wv * (9 * 32);
    const bf16_t* Bb    = wext + (h0 + mcol) * KP + quad * 8 + wv * (9 * 32);

    const int   er = tid >> 4, ec = tid & 15;
    const int   bat_e = mt * 16 + er;
    const int   h_e   = h0 + ec;
    const float bias_h = bias[h_e];
    float       hp = 0.f;              // f32 h_prev carried in-register (exact leak path)

    for (int t = 0; t < T_; ++t) {
        const bf16_t* cur = (t & 1) ? hbuf1 : hbuf0;
        bf16_t*       nxt = (t & 1) ? hbuf0 : hbuf1;

        // Stage x_{t+1} early (exclusive slot; readers blocked by next barrier).
        if (t + 1 < T_ && tid < 8) {
            int bx = bid >> 2;
            int d  = (bid & 3) * 16 + tid * 2;
            const float* xp = x + bx * (T_ * D_) + (t + 1) * D_ + d;
            __hip_atomic_store((unsigned*)(nxt + bx * KP + H_ + d), pack_bf16(xp[0], xp[1]),
                               __ATOMIC_RELAXED, __HIP_MEMORY_SCOPE_AGENT);
        }

        // A-frag: coherent (cache-bypassing) loads of cur h/x. B-frag: normal
        // cached loads of read-only Wext.
        const bf16_t* Ab = cur + a_off;
        f32x4 acc = {0.f, 0.f, 0.f, 0.f};
        #pragma unroll
        for (int kc = 0; kc < 9; ++kc) {
            union { u64 u[2]; bf16x8 v; } au;
            au.u[0] = __hip_atomic_load((const u64*)(Ab + kc * 32),
                                        __ATOMIC_RELAXED, __HIP_MEMORY_SCOPE_AGENT);
            au.u[1] = __hip_atomic_load((const u64*)(Ab + kc * 32 + 4),
                                        __ATOMIC_RELAXED, __HIP_MEMORY_SCOPE_AGENT);
            bf16x8 bv = *(const bf16x8*)(Bb + kc * 32);
            acc = __builtin_amdgcn_mfma_f32_16x16x32_bf16(au.v, bv, acc, 0, 0, 0);
        }

        // cross-wave K reduction via LDS. C/D layout: col=lane&15, row=quad*4+i
        #pragma unroll
        for (int i = 0; i < 4; ++i)
            lds[wv * 256 + (quad * 4 + i) * 16 + mcol] = acc[i];
        __syncthreads();

        {
            float u  = lds[tid] + lds[256 + tid] + lds[512 + tid] + lds[768 + tid] + bias_h;
            float th = tanhf(u);
            float hn = (1.f - LRATE) * hp + LRATE * th;
            hp = hn;
            out[bat_e * (T_ * H_) + t * H_ + h_e] = hn;     // hs[b, t, h] = h_{t+1}

            // coherent bf16 h store: pack pairs via shfl, even threads store u32
            unsigned hb = (unsigned)__builtin_bit_cast(unsigned short, (bf16_t)hn);
            unsigned ho = __shfl_down(hb, 1);
            if (!(tid & 1))
                __hip_atomic_store((unsigned*)(nxt + bat_e * KP + h_e), hb | (ho << 16),
                                   __ATOMIC_RELAXED, __HIP_MEMORY_SCOPE_AGENT);
        }

        if (t + 1 < T_)
            grid_barrier_fast(arrive, bid, tid, t + 2);
    }
}

extern "C" void kernel_launch(void* const* d_in, const int* in_sizes, int n_in,
                              void* d_out, int out_size, void* d_ws, size_t ws_size,
                              hipStream_t stream) {
    (void)in_sizes; (void)n_in; (void)out_size; (void)ws_size;
    const float* x    = (const float*)d_in[0];
    const float* Win  = (const float*)d_in[1];
    const float* bias = (const float*)d_in[2];
    const float* W    = (const float*)d_in[3];
    float*       out  = (float*)d_out;
    void*        ws   = d_ws;

    void* args[] = { (void*)&x, (void*)&Win, (void*)&bias, (void*)&W, (void*)&out, (void*)&ws };
    hipLaunchCooperativeKernel((const void*)esn_scan, dim3(GRID), dim3(NTHR), args, 0, stream);
}

// Round 3
// 6537.740 us; speedup vs baseline: 3.1399x; 1.1674x over previous
//
#include <hip/hip_runtime.h>
#include <hip/hip_bf16.h>

// ESN scan: h_{t+1} = 0.1*h_t + 0.9*tanh(x_t @ W_in^T + b + h_t @ W^T)
// B=32, T=1000, D_IN=64, H=1024. Persistent cooperative kernel, per-step grid
// barrier, bf16 MFMA with fused input projection.
// R3: (a) B-fragments held in registers for the entire scan (Wext is
// read-only after init), (b) A-fragments loaded with 9 back-to-back
// global_load_dwordx4 sc0 sc1 (one L3 round-trip instead of ~9 serialized),
// (c) all waves poll the barrier flags (one less __syncthreads), out-store
// moved off the critical path (after arrive-flag store), tight spin (no
// s_sleep). R2 lesson: VGPR_Count=32 meant the compiler serialized the
// 18 atomic A-loads -> ~9 L3 RTs/step on the serial chain.

#define B_    32
#define T_    1000
#define D_    64
#define H_    1024
#define KP    1152          // padded K: 1024 (h) + 64 (x) + 64 (zero pad)
#define GRID  128
#define NTHR  256
#define LRATE 0.9f

typedef __bf16 bf16_t;
typedef __bf16 bf16x8 __attribute__((ext_vector_type(8)));
typedef float  f32x4  __attribute__((ext_vector_type(4)));
typedef unsigned uint4v __attribute__((ext_vector_type(4)));
typedef unsigned long long u64;

// ws layout: arrive[256] ints @0 ; hbuf0 @1024 ; hbuf1 ; wext
#define HBUF_BYTES (B_ * KP * 2)
#define OFF_HBUF0  1024
#define OFF_HBUF1  (1024 + HBUF_BYTES)
#define OFF_WEXT   (1024 + 2 * HBUF_BYTES)

__device__ __forceinline__ unsigned pack_bf16(float a, float b) {
    unsigned short lo = __builtin_bit_cast(unsigned short, (bf16_t)a);
    unsigned short hi = __builtin_bit_cast(unsigned short, (bf16_t)b);
    return (unsigned)lo | ((unsigned)hi << 16);
}

// Init-only barrier: full release/acquire agent fences (makes the normally-
// stored Wext visible device-wide, once; after this Wext is read-only).
__device__ __forceinline__ void grid_barrier_fenced(int* arrive, int bid, int tid, int target) {
    __builtin_amdgcn_fence(__ATOMIC_RELEASE, "agent");
    __syncthreads();
    if (tid < 64) {
        if (tid == 0)
            __hip_atomic_store(&arrive[bid], target, __ATOMIC_RELAXED, __HIP_MEMORY_SCOPE_AGENT);
        for (;;) {
            int v0 = __hip_atomic_load(&arrive[tid],      __ATOMIC_RELAXED, __HIP_MEMORY_SCOPE_AGENT);
            int v1 = __hip_atomic_load(&arrive[tid + 64], __ATOMIC_RELAXED, __HIP_MEMORY_SCOPE_AGENT);
            if (__all((v0 >= target) & (v1 >= target))) break;
            __builtin_amdgcn_s_sleep(1);
        }
    }
    __syncthreads();
    __builtin_amdgcn_fence(__ATOMIC_ACQUIRE, "agent");
}

__global__ __launch_bounds__(NTHR, 1) void esn_scan(
    const float* __restrict__ x,     // [B, T, D]
    const float* __restrict__ Win,   // [H, D]
    const float* __restrict__ bias,  // [H]
    const float* __restrict__ W,     // [H, H]
    float* __restrict__ out,         // [B, T, H]
    unsigned char* wsb)
{
    int*    arrive = (int*)wsb;
    bf16_t* hbuf0  = (bf16_t*)(wsb + OFF_HBUF0);
    bf16_t* hbuf1  = (bf16_t*)(wsb + OFF_HBUF1);
    bf16_t* wext   = (bf16_t*)(wsb + OFF_WEXT);

    const int bid = blockIdx.x;
    const int tid = threadIdx.x;

    // ---------------- init phase ----------------
    // wext[h][0:1024]=W[h][:], [1024:1088]=Win[h][:], [1088:1152]=0  (bf16)
    {
        const int rows = H_ / GRID;           // 8 rows per block
        const int r0 = bid * rows;
        for (int r = r0; r < r0 + rows; ++r) {
            for (int c = tid; c < KP; c += NTHR) {
                float v = 0.f;
                if (c < H_)            v = W[r * H_ + c];
                else if (c < H_ + D_)  v = Win[r * D_ + (c - H_)];
                wext[r * KP + c] = (bf16_t)v;
            }
        }
        // hbuf rows: coherent atomic stores (read via sc loads each step).
        if (bid < B_) {
            for (int c = tid * 2; c < KP; c += NTHR * 2) {
                float v0 = 0.f, v1 = 0.f;
                if (c     >= H_ && c     < H_ + D_) v0 = x[bid * (T_ * D_) + (c     - H_)];
                if (c + 1 >= H_ && c + 1 < H_ + D_) v1 = x[bid * (T_ * D_) + (c + 1 - H_)];
                __hip_atomic_store((unsigned*)(hbuf0 + bid * KP + c), pack_bf16(v0, v1),
                                   __ATOMIC_RELAXED, __HIP_MEMORY_SCOPE_AGENT);
                __hip_atomic_store((unsigned*)(hbuf1 + bid * KP + c), 0u,
                                   __ATOMIC_RELAXED, __HIP_MEMORY_SCOPE_AGENT);
            }
        }
    }
    grid_barrier_fenced(arrive, bid, tid, 1);

    // ---------------- scan phase ----------------
    const int mt   = bid & 1;          // M-tile: batches [mt*16, mt*16+16)
    const int h0   = (bid >> 1) * 16;  // h-slice: [h0, h0+16)
    const int lane = tid & 63;
    const int wv   = tid >> 6;         // wave id 0..3 -> K quarter
    const int mcol = lane & 15;
    const int quad = lane >> 4;

    __shared__ float lds[4 * 256];

    const int a_off = (mt * 16 + mcol) * KP + quad * 8 + wv * (9 * 32);
    const bf16_t* Ab0 = hbuf0 + a_off;
    const bf16_t* Ab1 = hbuf1 + a_off;

    // B-fragments: load ONCE into registers (36 VGPRs); Wext is read-only
    // for the rest of the scan. Inner loop then touches no cached memory.
    uint4v breg[9];
    {
        const bf16_t* Bb = wext + (h0 + mcol) * KP + quad * 8 + wv * (9 * 32);
        #pragma unroll
        for (int kc = 0; kc < 9; ++kc)
            breg[kc] = *(const uint4v*)(Bb + kc * 32);
    }

    const int   er = tid >> 4, ec = tid & 15;
    const int   bat_e = mt * 16 + er;
    const int   h_e   = h0 + ec;
    const float bias_h = bias[h_e];
    float*      outp   = out + bat_e * (T_ * H_) + h_e;   // advances by H_ per step
    float       hp = 0.f;              // f32 h_prev carried in-register

    for (int t = 0; t < T_; ++t) {
        const bf16_t* Ab  = (t & 1) ? Ab1 : Ab0;
        bf16_t*       nxt = (t & 1) ? hbuf0 : hbuf1;

        // Stage x_{t+1} into nxt's x-region (dead until after next barrier;
        // drained by this step's pre-flag waitcnt). Off critical path.
        if (t + 1 < T_ && tid < 8) {
            int bx = bid >> 2;
            int d  = (bid & 3) * 16 + tid * 2;
            const float* xp = x + bx * (T_ * D_) + (t + 1) * D_ + d;
            __hip_atomic_store((unsigned*)(nxt + bx * KP + H_ + d), pack_bf16(xp[0], xp[1]),
                               __ATOMIC_RELAXED, __HIP_MEMORY_SCOPE_AGENT);
        }

        // A-fragments: 9 back-to-back coherent 16B loads -> ONE L3 round-trip.
        uint4v a0, a1, a2, a3, a4, a5, a6, a7, a8;
        {
            #define ALOAD(reg, idx) \
                { const bf16_t* p_ = Ab + (idx) * 32; \
                  asm volatile("global_load_dwordx4 %0, %1, off sc0 sc1" \
                               : "=&v"(reg) : "v"(p_) : "memory"); }
            ALOAD(a0, 0) ALOAD(a1, 1) ALOAD(a2, 2) ALOAD(a3, 3) ALOAD(a4, 4)
            ALOAD(a5, 5) ALOAD(a6, 6) ALOAD(a7, 7) ALOAD(a8, 8)
            #undef ALOAD
            // Tie results through the waitcnt so no consumer floats above it.
            asm volatile("s_waitcnt vmcnt(0)"
                         : "+v"(a0), "+v"(a1), "+v"(a2), "+v"(a3), "+v"(a4),
                           "+v"(a5), "+v"(a6), "+v"(a7), "+v"(a8)
                         :: "memory");
        }

        f32x4 acc = {0.f, 0.f, 0.f, 0.f};
        #define AMFMA(reg, idx) \
            acc = __builtin_amdgcn_mfma_f32_16x16x32_bf16( \
                __builtin_bit_cast(bf16x8, reg), __builtin_bit_cast(bf16x8, breg[idx]), acc, 0, 0, 0);
        AMFMA(a0, 0) AMFMA(a1, 1) AMFMA(a2, 2) AMFMA(a3, 3) AMFMA(a4, 4)
        AMFMA(a5, 5) AMFMA(a6, 6) AMFMA(a7, 7) AMFMA(a8, 8)
        #undef AMFMA

        // cross-wave K reduction via LDS. C/D layout: col=lane&15, row=quad*4+i
        #pragma unroll
        for (int i = 0; i < 4; ++i)
            lds[wv * 256 + (quad * 4 + i) * 16 + mcol] = acc[i];
        __syncthreads();

        float u  = lds[tid] + lds[256 + tid] + lds[512 + tid] + lds[768 + tid] + bias_h;
        float th = tanhf(u);
        float hn = (1.f - LRATE) * hp + LRATE * th;
        hp = hn;

        // coherent bf16 h store: pack pairs via shfl, even threads store u32
        unsigned hb = (unsigned)__builtin_bit_cast(unsigned short, (bf16_t)hn);
        unsigned ho = __shfl_down(hb, 1);
        if (!(tid & 1))
            __hip_atomic_store((unsigned*)(nxt + bat_e * KP + h_e), hb | (ho << 16),
                               __ATOMIC_RELAXED, __HIP_MEMORY_SCOPE_AGENT);

        if (t + 1 < T_) {
            // Drain h-store (and x-stage) acks, then publish arrival.
            __builtin_amdgcn_s_waitcnt(0);
            __syncthreads();
            if (tid == 0)
                __hip_atomic_store(&arrive[bid], t + 2, __ATOMIC_RELAXED, __HIP_MEMORY_SCOPE_AGENT);
            outp[t * H_] = hn;                 // out-store off the critical path
            // ALL waves poll (no trailing __syncthreads needed).
            const int target = t + 2;
            for (;;) {
                int v0 = __hip_atomic_load(&arrive[lane],      __ATOMIC_RELAXED, __HIP_MEMORY_SCOPE_AGENT);
                int v1 = __hip_atomic_load(&arrive[lane + 64], __ATOMIC_RELAXED, __HIP_MEMORY_SCOPE_AGENT);
                if (__all((v0 >= target) & (v1 >= target))) break;
            }
        } else {
            outp[t * H_] = hn;
        }
    }
}

extern "C" void kernel_launch(void* const* d_in, const int* in_sizes, int n_in,
                              void* d_out, int out_size, void* d_ws, size_t ws_size,
                              hipStream_t stream) {
    (void)in_sizes; (void)n_in; (void)out_size; (void)ws_size;
    const float* x    = (const float*)d_in[0];
    const float* Win  = (const float*)d_in[1];
    const float* bias = (const float*)d_in[2];
    const float* W    = (const float*)d_in[3];
    float*       out  = (float*)d_out;
    void*        ws   = d_ws;

    void* args[] = { (void*)&x, (void*)&Win, (void*)&bias, (void*)&W, (void*)&out, (void*)&ws };
    hipLaunchCooperativeKernel((const void*)esn_scan, dim3(GRID), dim3(NTHR), args, 0, stream);
}